// Round 1
// baseline (67.129 us; speedup 1.0000x reference)
//
#include <hip/hip_runtime.h>
#include <hip/hip_bf16.h>

// Problem constants (from reference)
#define UNITS 512
#define CONN  512
#define SEQL  32

typedef __hip_bfloat16 bf16;
typedef __attribute__((ext_vector_type(8))) short short8;   // 8 bf16 = MFMA A/B frag
typedef __attribute__((ext_vector_type(4))) float floatx4;  // MFMA C/D frag

// out[b,u] = relu( sum_c x[b,c] * kernel[u] * dendriticW[dendrites[u,c], u] + bias[u] )
// == 512^3 GEMM with gather-built weights, bf16 MFMA (absmax 1.95e-3 vs 9.84e-3,
// measured in prior rounds).
//
// R6: single fused kernel, ZERO workspace use. Rationale (rocprof): the timed
// region of the two-kernel path carried a 256 MB fillBufferAligned ws-poison
// (40.4 us @ 83% HBM peak) + two launches + a 1 MB W/xb HBM round-trip.
// vs the old R5 fused fallback, two fixes:
//   1) per-block LDS dW table (kv-folded, 2 KB) -- replaces 8K scattered
//      global dW gathers per block with one coalesced 2 KB load + LDS lookups
//      (random over 32 banks ~ 2-way = free). Same trick that made prep fast.
//   2) A-fragment preload: all 32 x loads issued BEFORE the table/W-tile
//      barriers, so global latency hides under the W build.
// MFMA fragment/store mappings copied verbatim from the R5-proven kernel.

union cv8 { bf16 h[8]; short8 v; };

__device__ __forceinline__ short8 cvt8(const float* p) {
    const float4 f0 = ((const float4*)p)[0];
    const float4 f1 = ((const float4*)p)[1];
    cv8 a;
    a.h[0] = __float2bfloat16(f0.x); a.h[1] = __float2bfloat16(f0.y);
    a.h[2] = __float2bfloat16(f0.z); a.h[3] = __float2bfloat16(f0.w);
    a.h[4] = __float2bfloat16(f1.x); a.h[5] = __float2bfloat16(f1.y);
    a.h[6] = __float2bfloat16(f1.z); a.h[7] = __float2bfloat16(f1.w);
    return a.v;
}

// Grid: (UNITS/16, batch/64), 256 threads = 4 waves. Each block: 16 units x
// 64 batch rows. Each wave: one 16x16 output tile over K=512 (16 MFMAs).
__global__ __launch_bounds__(256) void dendriter_fused_v2(
    const float* __restrict__ x,     // [batch*CONN] fp32
    const float* __restrict__ kern,  // [UNITS] fp32 (per-unit scalar)
    const float* __restrict__ dW,    // [SEQL*UNITS] fp32
    const float* __restrict__ bias,  // [UNITS] fp32
    const int*   __restrict__ dend,  // [UNITS*CONN] int32 segment ids
    float* __restrict__ out)         // [batch*UNITS] fp32
{
    __shared__ float  table[16][SEQL];  // kv*dW column per tile-unit (2 KB)
    __shared__ short8 wl[16][65];       // bf16 W tile: 16 units x 512 conns (16.6 KB)

    const int t  = threadIdx.x;
    const int ut = blockIdx.x * 16;
    const int bt = blockIdx.y * 64;

    // ---- A preload: issue all x loads first; latency hides under W build ----
    const int lane = t & 63;
    const int wv   = t >> 6;            // wave id 0..3 -> batch sub-tile
    const int m    = lane & 15;         // A row / C unit-col (m89-verified maps)
    const int q    = lane >> 4;         // k-quarter / C row-group
    const int btw  = bt + wv * 16;
    const float* xrow = x + (size_t)(btw + m) * CONN + q * 8;
    short8 afr[16];
#pragma unroll
    for (int kb = 0; kb < 16; ++kb)
        afr[kb] = cvt8(xrow + kb * 32);     // 64 VGPRs, held across barriers

    // ---- dW table: coalesced 2 KB load, kv folded in ----
#pragma unroll
    for (int e = t; e < 16 * SEQL; e += 256) {   // 2 iters
        const int seg = e >> 4, ul = e & 15;     // consecutive t -> consecutive u
        table[ul][seg] = kern[ut + ul] * dW[seg * UNITS + ut + ul];
    }
    __syncthreads();

    // ---- W tile build: dend coalesced int4 pairs, gather from LDS table ----
    {
        const int ul  = t >> 4;                  // unit 0..15
        const int cg0 = (t & 15) * 4;            // 4 column-groups of 8 conns
        const int4* dp = (const int4*)(dend + (size_t)(ut + ul) * CONN + cg0 * 8);
#pragma unroll
        for (int j = 0; j < 4; ++j) {
            const int4 s0 = dp[2 * j];
            const int4 s1 = dp[2 * j + 1];
            const int segs[8] = {s0.x, s0.y, s0.z, s0.w, s1.x, s1.y, s1.z, s1.w};
            cv8 w;
#pragma unroll
            for (int i = 0; i < 8; ++i)          // LDS lookup, ~2-way banks (free)
                w.h[i] = __float2bfloat16(table[ul][segs[i]]);
            const int cg = cg0 + j;
            wl[cg >> 2][ul | ((cg & 3) << 4)] = w.v;   // R5-proven B layout
        }
    }
    __syncthreads();

    // ---- MFMA: B read wl[kb][lane] is exactly 2-way banked (free) ----
    floatx4 acc = {0.f, 0.f, 0.f, 0.f};
#pragma unroll
    for (int kb = 0; kb < 16; ++kb)
        acc = __builtin_amdgcn_mfma_f32_16x16x32_bf16(afr[kb], wl[kb][lane],
                                                      acc, 0, 0, 0);

    // ---- epilogue: bias + relu, C/D map col=lane&15(unit), row=q*4+r(batch) ----
    const float bu = bias[ut + m];
#pragma unroll
    for (int r = 0; r < 4; ++r) {
        float v = acc[r] + bu;
        v = v > 0.f ? v : 0.f;
        out[(size_t)(btw + q * 4 + r) * UNITS + ut + m] = v;
    }
}

extern "C" void kernel_launch(void* const* d_in, const int* in_sizes, int n_in,
                              void* d_out, int out_size, void* d_ws, size_t ws_size,
                              hipStream_t stream) {
    // setup_inputs() order: x, kernel, dendriticW, bias, dendrites — all fp32
    const float* x    = (const float*)d_in[0];
    const float* kern = (const float*)d_in[1];
    const float* dW   = (const float*)d_in[2];
    const float* bias = (const float*)d_in[3];
    const int*   dend = (const int*)  d_in[4];
    float* out = (float*)d_out;

    const int batch = in_sizes[0] / CONN;   // 512
    (void)d_ws; (void)ws_size;              // deliberately unused: no ws poison dep

    dendriter_fused_v2<<<dim3(UNITS / 16, batch / 64), 256, 0, stream>>>(
        x, kern, dW, bias, dend, out);
}